// Round 3
// baseline (246.586 us; speedup 1.0000x reference)
//
#include <hip/hip_runtime.h>

#define BSZ   32768
#define H     512
#define K1DIM 532      // H + 20
#define KPAD  544      // padded to multiple of 32 (ws path)
#define ASTR  552      // LDS A row stride in shorts
#define CD    1024
#define NCATS 262144
#define MV    1000
#define LNEPS 1e-6f

typedef short bf16x8 __attribute__((ext_vector_type(8)));   // 8 bf16 in 4 VGPRs
typedef float f32x4  __attribute__((ext_vector_type(4)));

__device__ __forceinline__ unsigned short f2bf(float x) {
    unsigned int u = __float_as_uint(x);
    u += 0x7FFFu + ((u >> 16) & 1u);        // RNE
    return (unsigned short)(u >> 16);
}

// pack two fp32 -> two bf16 (truncate) in one v_perm
__device__ __forceinline__ unsigned int pack_bf2(float lo, float hi) {
    return __builtin_amdgcn_perm(__float_as_uint(hi), __float_as_uint(lo), 0x07060302u);
}

// ---------- prep (ws path only): mlp1_w fp32 [1024][532] -> bf16 [1024][544] ----------
__global__ void k_prep_w1(const float* __restrict__ w1, unsigned short* __restrict__ w1b) {
    int idx = blockIdx.x * blockDim.x + threadIdx.x;
    if (idx >= CD * KPAD) return;
    int row = idx / KPAD, k = idx - row * KPAD;
    float v = (k < K1DIM) ? w1[row * K1DIM + k] : 0.f;
    w1b[idx] = f2bf(v);
}

// ---------- fully fused classifier ----------
template <bool USEWS>
__global__ __launch_bounds__(512, 2) void k_main(
    const float* __restrict__ encode, const float* __restrict__ credit,
    const float* __restrict__ meta_table, const float* __restrict__ conv_w,
    const float* __restrict__ conv_b, const float* __restrict__ ln1_g,
    const float* __restrict__ ln1_b, const float* __restrict__ w1f,
    const unsigned short* __restrict__ w1b, const float* __restrict__ b1,
    const float* __restrict__ ln2_g, const float* __restrict__ ln2_b,
    const float* __restrict__ out_w, const float* __restrict__ out_b,
    const int* __restrict__ meta_ids, const int* __restrict__ cat_ids,
    const int* __restrict__ cat_seg, float* __restrict__ out)
{
    __shared__ unsigned short Alds[64 * ASTR];   // 70656 B
    __shared__ float Vlds[6 * CD];               // 24576 B
    __shared__ float gL[K1DIM], bL[K1DIM];
    __shared__ float cwL[90], cbL[5];
    __shared__ float mfL[64][20];
    __shared__ float sEnc[64], qEnc[64];
    __shared__ float muL[64], rsL[64];
    __shared__ float rowsum[64][8], rowsq[64][8];
    __shared__ float mu2[64], rs2[64];
    __shared__ float Sbuf[64][6][8];
    __shared__ float c0L[6], c1L[6];
    __shared__ int   startsL[65];
    __shared__ int   sLoL, sHiL;

    const int tid  = threadIdx.x;
    const int row0 = blockIdx.x * 64;
    const int lane = tid & 63;
    const int w    = tid >> 6;

    // ---- P0: boundary searches (wave 0 lanes 0,1) || Vlds/gL/bL/conv + encode stats (waves 1..7)
    if (w == 0) {
        if (lane < 2) {
            int target = row0 + lane * 64;
            int lo = 0, hi = NCATS;
            while (lo < hi) { int mid = (lo + hi) >> 1; if (cat_seg[mid] < target) lo = mid + 1; else hi = mid; }
            if (lane == 0) sLoL = lo; else sHiL = lo;
        }
    } else {
        const int t = tid - 64;
        for (int i = t; i < 6 * CD; i += 448) Vlds[i] = ln2_g[i & (CD - 1)] * out_w[i];
        for (int i = t; i < K1DIM; i += 448) { gL[i] = ln1_g[i]; bL[i] = ln1_b[i]; }
        if (t < 90) cwL[t] = conv_w[t];
        if (t < 5)  cbL[t] = conv_b[t];
        for (int r = w - 1; r < 64; r += 7) {
            const float* p = encode + (size_t)(row0 + r) * H + lane * 8;
            float4 v0 = *(const float4*)p;
            float4 v1 = *(const float4*)(p + 4);
            float s = v0.x + v0.y + v0.z + v0.w + v1.x + v1.y + v1.z + v1.w;
            float q = v0.x*v0.x + v0.y*v0.y + v0.z*v0.z + v0.w*v0.w
                    + v1.x*v1.x + v1.y*v1.y + v1.z*v1.z + v1.w*v1.w;
            for (int m = 1; m < 64; m <<= 1) { s += __shfl_xor(s, m); q += __shfl_xor(q, m); }
            if (lane == 0) { sEnc[r] = s; qEnc[r] = q; }
        }
    }
    __syncthreads();

    // ---- P1: parallel boundary scan (all threads) + c0/c1 reductions (waves 1..6)
    {
        const int slo = sLoL, shi = sHiL;
        for (int i = slo - 1 + tid; i < shi; i += 512) {
            int a = (i >= 0) ? cat_seg[i] : -1;
            int b = (i + 1 < NCATS) ? cat_seg[i + 1] : BSZ;
            int rlo = max(a + 1, row0);
            int rhi = min(b, row0 + 64);
            for (int r = rlo; r <= rhi; ++r) startsL[r - row0] = i + 1;
        }
    }
    if (w >= 1 && w <= 6) {
        int j = w - 1;
        float s1 = 0.f, s0 = 0.f;
        for (int c = lane; c < CD; c += 64) {
            s1 += Vlds[j * CD + c];
            s0 = fmaf(ln2_b[c], out_w[j * CD + c], s0);
        }
        for (int m = 1; m < 64; m <<= 1) { s1 += __shfl_xor(s1, m); s0 += __shfl_xor(s0, m); }
        if (lane == 0) { c1L[j] = s1; c0L[j] = s0 + out_b[j]; }
    }
    __syncthreads();

    // ---- P2: per-row meta features + LN1 finalize (threads 0..63)
    if (tid < 64) {
        const int r = tid;
        const int s = startsL[r], e = startsL[r + 1];
        float mm[6][8];
        float sum[8];
        #pragma unroll
        for (int d = 0; d < 8; d++) sum[d] = 0.f;
        for (int i = s; i < e; i++) {
            int id = cat_ids[i];
            const float4 a = *(const float4*)(meta_table + (size_t)id * 8);
            const float4 b = *(const float4*)(meta_table + (size_t)id * 8 + 4);
            sum[0] += a.x; sum[1] += a.y; sum[2] += a.z; sum[3] += a.w;
            sum[4] += b.x; sum[5] += b.y; sum[6] += b.z; sum[7] += b.w;
        }
        float cnt = fmaxf((float)(e - s), 1.f);
        #pragma unroll
        for (int d = 0; d < 8; d++) mm[0][d] = sum[d] / cnt;
        #pragma unroll
        for (int i = 0; i < 5; i++) {
            int id = meta_ids[(size_t)(row0 + r) * 5 + i];
            const float4 a = *(const float4*)(meta_table + (size_t)id * 8);
            const float4 b = *(const float4*)(meta_table + (size_t)id * 8 + 4);
            mm[1+i][0] = a.x; mm[1+i][1] = a.y; mm[1+i][2] = a.z; mm[1+i][3] = a.w;
            mm[1+i][4] = b.x; mm[1+i][5] = b.y; mm[1+i][6] = b.z; mm[1+i][7] = b.w;
        }
        float mfv[20];
        #pragma unroll
        for (int oc = 0; oc < 5; oc++) {
            float c[6];
            #pragma unroll
            for (int x = 0; x < 6; x++) {
                float a = cbL[oc];
                #pragma unroll
                for (int ic = 0; ic < 6; ic++)
                    #pragma unroll
                    for (int k = 0; k < 3; k++)
                        a = fmaf(mm[ic][x + k], cwL[(oc * 6 + ic) * 3 + k], a);
                c[x] = fmaxf(a, 0.f);
            }
            #pragma unroll
            for (int x = 0; x < 4; x++)
                mfv[oc * 4 + x] = fmaxf(fmaxf(c[x], c[x + 1]), c[x + 2]);
        }
        float sT = sEnc[r], qT = qEnc[r];
        #pragma unroll
        for (int j = 0; j < 20; j++) {
            mfL[r][j] = mfv[j];
            sT += mfv[j]; qT = fmaf(mfv[j], mfv[j], qT);
        }
        float mean = sT * (1.f / K1DIM);
        float var  = qT * (1.f / K1DIM) - mean * mean;
        muL[r] = mean;
        rsL[r] = rsqrtf(var + LNEPS);
    }
    __syncthreads();

    // ---- P3: stage A = LN1-normalized bf16 tile (encode re-read is L2-hot)
    for (int i = tid; i < 64 * 136; i += 512) {
        int r = i / 136, c4 = i - r * 136;
        int col = c4 * 4;
        unsigned short o0 = 0, o1 = 0, o2 = 0, o3 = 0;
        if (c4 < 133) {
            float x0, x1, x2, x3;
            if (c4 < 128) {
                const float4 v = *(const float4*)&encode[(size_t)(row0 + r) * H + col];
                x0 = v.x; x1 = v.y; x2 = v.z; x3 = v.w;
            } else {
                int o = col - H;
                x0 = mfL[r][o]; x1 = mfL[r][o + 1]; x2 = mfL[r][o + 2]; x3 = mfL[r][o + 3];
            }
            float m = muL[r], rr = rsL[r];
            o0 = f2bf((x0 - m) * rr * gL[col + 0] + bL[col + 0]);
            o1 = f2bf((x1 - m) * rr * gL[col + 1] + bL[col + 1]);
            o2 = f2bf((x2 - m) * rr * gL[col + 2] + bL[col + 2]);
            o3 = f2bf((x3 - m) * rr * gL[col + 3] + bL[col + 3]);
        }
        ushort4 st = { o0, o1, o2, o3 };
        *(ushort4*)&Alds[r * ASTR + col] = st;
    }
    __syncthreads();

    // ---- GEMM1: 64 rows x 1024 cols, K=532(544). A from LDS, B from global (L2-resident).
    const int ln   = lane & 15;
    const int quad = lane >> 4;
    const int cb   = w * 128;

    f32x4 acc[4][8];
    #pragma unroll
    for (int rt = 0; rt < 4; rt++)
        #pragma unroll
        for (int ct = 0; ct < 8; ct++)
            acc[rt][ct] = f32x4{0.f, 0.f, 0.f, 0.f};

    const int KK = USEWS ? 17 : 16;
    #pragma unroll 1
    for (int kk = 0; kk < KK; kk++) {
        bf16x8 af[4];
        #pragma unroll
        for (int rt = 0; rt < 4; rt++)
            af[rt] = *(const bf16x8*)&Alds[(rt * 16 + ln) * ASTR + kk * 32 + quad * 8];
        #pragma unroll
        for (int ct = 0; ct < 8; ct++) {
            bf16x8 bfr;
            if constexpr (USEWS) {
                bfr = *(const bf16x8*)(w1b + (size_t)(cb + ct * 16 + ln) * KPAD + kk * 32 + quad * 8);
            } else {
                const float* wrow = w1f + (size_t)(cb + ct * 16 + ln) * K1DIM + kk * 32 + quad * 8;
                const float4 fa = *(const float4*)wrow;
                const float4 fb = *(const float4*)(wrow + 4);
                union { bf16x8 v; unsigned int u[4]; } bu;
                bu.u[0] = pack_bf2(fa.x, fa.y);
                bu.u[1] = pack_bf2(fa.z, fa.w);
                bu.u[2] = pack_bf2(fb.x, fb.y);
                bu.u[3] = pack_bf2(fb.z, fb.w);
                bfr = bu.v;
            }
            #pragma unroll
            for (int rt = 0; rt < 4; rt++)
                acc[rt][ct] = __builtin_amdgcn_mfma_f32_16x16x32_bf16(af[rt], bfr, acc[rt][ct], 0, 0, 0);
        }
    }
    if constexpr (!USEWS) {
        // K-tail: k in [512,544); valid only [512,532) — A is zero for k>=532
        bf16x8 af[4];
        #pragma unroll
        for (int rt = 0; rt < 4; rt++)
            af[rt] = *(const bf16x8*)&Alds[(rt * 16 + ln) * ASTR + 512 + quad * 8];
        #pragma unroll
        for (int ct = 0; ct < 8; ct++) {
            union { bf16x8 v; unsigned int u[4]; } bu;
            bu.u[0] = 0; bu.u[1] = 0; bu.u[2] = 0; bu.u[3] = 0;
            const float* wrow = w1f + (size_t)(cb + ct * 16 + ln) * K1DIM + 512 + quad * 8;
            if (quad < 2) {
                const float4 fa = *(const float4*)wrow;
                const float4 fb = *(const float4*)(wrow + 4);
                bu.u[0] = pack_bf2(fa.x, fa.y);
                bu.u[1] = pack_bf2(fa.z, fa.w);
                bu.u[2] = pack_bf2(fb.x, fb.y);
                bu.u[3] = pack_bf2(fb.z, fb.w);
            } else if (quad == 2) {
                const float4 fa = *(const float4*)wrow;   // cols 528..531 (in-bounds)
                bu.u[0] = pack_bf2(fa.x, fa.y);
                bu.u[1] = pack_bf2(fa.z, fa.w);
            }
            #pragma unroll
            for (int rt = 0; rt < 4; rt++)
                acc[rt][ct] = __builtin_amdgcn_mfma_f32_16x16x32_bf16(af[rt], bu.v, acc[rt][ct], 0, 0, 0);
        }
    }

    // ---- epilogue: +b1, ReLU (C/D layout: col = ln, row = quad*4 + reg)
    float b1v[8]; int colc[8];
    #pragma unroll
    for (int ct = 0; ct < 8; ct++) { colc[ct] = cb + ct * 16 + ln; b1v[ct] = b1[colc[ct]]; }
    #pragma unroll
    for (int rt = 0; rt < 4; rt++)
        #pragma unroll
        for (int ct = 0; ct < 8; ct++)
            #pragma unroll
            for (int reg = 0; reg < 4; reg++)
                acc[rt][ct][reg] = fmaxf(acc[rt][ct][reg] + b1v[ct], 0.f);

    // LN2 row stats
    #pragma unroll
    for (int rt = 0; rt < 4; rt++) {
        #pragma unroll
        for (int reg = 0; reg < 4; reg++) {
            float s = 0.f, q = 0.f;
            #pragma unroll
            for (int ct = 0; ct < 8; ct++) { float f = acc[rt][ct][reg]; s += f; q = fmaf(f, f, q); }
            #pragma unroll
            for (int m = 1; m <= 8; m <<= 1) { s += __shfl_xor(s, m); q += __shfl_xor(q, m); }
            if (ln == 0) {
                int row = rt * 16 + quad * 4 + reg;
                rowsum[row][w] = s; rowsq[row][w] = q;
            }
        }
    }
    __syncthreads();
    if (tid < 64) {
        float s = 0.f, q = 0.f;
        #pragma unroll
        for (int ww = 0; ww < 8; ww++) { s += rowsum[tid][ww]; q += rowsq[tid][ww]; }
        float mean = s * (1.f / CD);
        float var  = q * (1.f / CD) - mean * mean;
        mu2[tid] = mean; rs2[tid] = rsqrtf(var + LNEPS);
    }

    // GEMM2 partials over this wave's 128 cols
    float vv[6][8];
    #pragma unroll
    for (int j = 0; j < 6; j++)
        #pragma unroll
        for (int ct = 0; ct < 8; ct++)
            vv[j][ct] = Vlds[j * CD + colc[ct]];
    #pragma unroll
    for (int rt = 0; rt < 4; rt++) {
        #pragma unroll
        for (int reg = 0; reg < 4; reg++) {
            float p0 = 0.f, p1 = 0.f, p2 = 0.f, p3 = 0.f, p4 = 0.f, p5 = 0.f;
            #pragma unroll
            for (int ct = 0; ct < 8; ct++) {
                float f = acc[rt][ct][reg];
                p0 = fmaf(f, vv[0][ct], p0); p1 = fmaf(f, vv[1][ct], p1);
                p2 = fmaf(f, vv[2][ct], p2); p3 = fmaf(f, vv[3][ct], p3);
                p4 = fmaf(f, vv[4][ct], p4); p5 = fmaf(f, vv[5][ct], p5);
            }
            #pragma unroll
            for (int m = 1; m <= 8; m <<= 1) {
                p0 += __shfl_xor(p0, m); p1 += __shfl_xor(p1, m); p2 += __shfl_xor(p2, m);
                p3 += __shfl_xor(p3, m); p4 += __shfl_xor(p4, m); p5 += __shfl_xor(p5, m);
            }
            if (ln == 0) {
                int row = rt * 16 + quad * 4 + reg;
                Sbuf[row][0][w] = p0; Sbuf[row][1][w] = p1; Sbuf[row][2][w] = p2;
                Sbuf[row][3][w] = p3; Sbuf[row][4][w] = p4; Sbuf[row][5][w] = p5;
            }
        }
    }
    __syncthreads();

    // combine: out = rs2*S - mu2*rs2*c1[j] + c0[j] + credit-bias
    if (tid < 384) {
        int r = tid / 6, j = tid - r * 6;
        float S = 0.f;
        #pragma unroll
        for (int ww = 0; ww < 8; ww++) S += Sbuf[r][j][ww];
        int gr = row0 + r;
        float cs = 0.f;
        #pragma unroll
        for (int jj = 0; jj < 6; jj++) cs += credit[(size_t)gr * 6 + jj];
        float bias = (cs > 0.f) ? credit[(size_t)gr * 6 + j] / cs : (1.f / 6.f);
        out[(size_t)gr * 6 + j] = rs2[r] * S - mu2[r] * rs2[r] * c1L[j] + c0L[j] + bias;
    }
}

extern "C" void kernel_launch(void* const* d_in, const int* in_sizes, int n_in,
                              void* d_out, int out_size, void* d_ws, size_t ws_size,
                              hipStream_t stream) {
    const float* encode     = (const float*)d_in[0];
    const float* credit     = (const float*)d_in[1];
    const float* meta_table = (const float*)d_in[2];
    const float* conv_w     = (const float*)d_in[3];
    const float* conv_b     = (const float*)d_in[4];
    const float* ln1_g      = (const float*)d_in[5];
    const float* ln1_b      = (const float*)d_in[6];
    const float* mlp1_w     = (const float*)d_in[7];
    const float* mlp1_b     = (const float*)d_in[8];
    const float* ln2_g      = (const float*)d_in[9];
    const float* ln2_b      = (const float*)d_in[10];
    const float* out_w      = (const float*)d_in[11];
    const float* out_b      = (const float*)d_in[12];
    const int*   meta_ids   = (const int*)d_in[13];
    const int*   cat_ids    = (const int*)d_in[14];
    const int*   cat_seg    = (const int*)d_in[15];
    float* out = (float*)d_out;

    const size_t W1B_BYTES = (size_t)CD * KPAD * sizeof(unsigned short);  // 1,114,112
    if (ws_size >= W1B_BYTES) {
        unsigned short* w1b = (unsigned short*)d_ws;
        k_prep_w1<<<(CD * KPAD + 255) / 256, 256, 0, stream>>>(mlp1_w, w1b);
        k_main<true><<<BSZ / 64, 512, 0, stream>>>(
            encode, credit, meta_table, conv_w, conv_b, ln1_g, ln1_b,
            mlp1_w, w1b, mlp1_b, ln2_g, ln2_b, out_w, out_b,
            meta_ids, cat_ids, cat_seg, out);
    } else {
        k_main<false><<<BSZ / 64, 512, 0, stream>>>(
            encode, credit, meta_table, conv_w, conv_b, ln1_g, ln1_b,
            mlp1_w, (const unsigned short*)nullptr, mlp1_b, ln2_g, ln2_b, out_w, out_b,
            meta_ids, cat_ids, cat_seg, out);
    }
}